// Round 2
// baseline (4342.359 us; speedup 1.0000x reference)
//
#include <hip/hip_runtime.h>
#include <math.h>
#include <stdint.h>

#define STEPS 127
#define NBLK 64
#define NTHR 256
#define CAP 160

struct GDParams {
  const int* node_types; const int* esrc; const int* edst; const float* he;
  const float* enc_W; const float* enc_b; const float* msg_W; const float* msg_b;
  const float* Wih; const float* Whh; const float* bih; const float* bhh;
  unsigned* bar;          // [0]=counter [1]=generation (memset 0 pre-launch)
  float* buf0; float* buf1;
  float* g;               // 16256 gumbel values
  float* WqT; float* WrT; float* WhhT;   // [2][128][384] k-major folded weights
  float* W2T;             // [2][16][384]
  float* bm2;             // [2][384]
  float* HeSum;           // [127][128][16]
  float* degs;            // [127][128]
  unsigned char* alive;   // [127][128]
  unsigned char* hasE;    // [127]
  int* victims; int* row_ptr; int* in_count; int* cursor; int* col_src; int* col_eid;
  int* misc;              // [0] = survivor
  float* out;             // 257 floats: hv[surv](128) | victim_order(128) | logps(1)
};

__device__ __forceinline__ void tfround(unsigned &x0, unsigned &x1, int r) {
  x0 += x1; x1 = (x1 << r) | (x1 >> (32 - r)); x1 ^= x0;
}
__device__ void threefry2x32(unsigned k0, unsigned k1, unsigned c0, unsigned c1,
                             unsigned &o0, unsigned &o1) {
  unsigned ks2 = k0 ^ k1 ^ 0x1BD11BDAu;
  unsigned x0 = c0 + k0, x1 = c1 + k1;
  tfround(x0,x1,13); tfround(x0,x1,15); tfround(x0,x1,26); tfround(x0,x1,6);
  x0 += k1; x1 += ks2 + 1u;
  tfround(x0,x1,17); tfround(x0,x1,29); tfround(x0,x1,16); tfround(x0,x1,24);
  x0 += ks2; x1 += k0 + 2u;
  tfround(x0,x1,13); tfround(x0,x1,15); tfround(x0,x1,26); tfround(x0,x1,6);
  x0 += k0; x1 += k1 + 3u;
  tfround(x0,x1,17); tfround(x0,x1,29); tfround(x0,x1,16); tfround(x0,x1,24);
  x0 += k1; x1 += ks2 + 4u;
  tfround(x0,x1,13); tfround(x0,x1,15); tfround(x0,x1,26); tfround(x0,x1,6);
  x0 += ks2; x1 += k0 + 5u;
  o0 = x0; o1 = x1;
}
__device__ __forceinline__ float gumbel_from_bits(unsigned b) {
  // exact replication of jax _uniform + _gumbel bit transform (f32)
  unsigned fb = (b >> 9) | 0x3F800000u;
  float f = __uint_as_float(fb) - 1.0f;
  const float tiny = 1.17549435e-38f;
  float u = fmaxf(tiny, f * (1.0f - tiny) + tiny);
  return -logf(-logf(u));
}

__device__ __forceinline__ void gsync(unsigned* bar, unsigned &mygen) {
  __syncthreads();
  mygen++;
  if (threadIdx.x == 0) {
    unsigned prev = __hip_atomic_fetch_add(&bar[0], 1u, __ATOMIC_ACQ_REL, __HIP_MEMORY_SCOPE_AGENT);
    if (prev == (unsigned)(gridDim.x - 1u)) {
      __hip_atomic_store(&bar[0], 0u, __ATOMIC_RELAXED, __HIP_MEMORY_SCOPE_AGENT);
      __hip_atomic_store(&bar[1], mygen, __ATOMIC_RELEASE, __HIP_MEMORY_SCOPE_AGENT);
    } else {
      long guard = 0;
      while (__hip_atomic_load(&bar[1], __ATOMIC_ACQUIRE, __HIP_MEMORY_SCOPE_AGENT) != mygen) {
        if (++guard > (1L << 30)) break;   // safety valve against hang
      }
    }
  }
  __syncthreads();
}

__global__ __launch_bounds__(NTHR, 1) void gd_main(GDParams p) {
  __shared__ alignas(16) float S_lds[2][128];
  __shared__ alignas(16) float hv_lds[2][128];
  __shared__ float He_lds[2][16];
  __shared__ float pgi[1536];   // [v][384][h]
  __shared__ float pgh[1536];
  __shared__ int colL[2][CAP];
  __shared__ int cntL[2]; __shared__ int rpL[2];
  __shared__ float degL[2]; __shared__ int aliveL[2];
  __shared__ int victimL; __shared__ int hasEL;
  __shared__ int pfs[128];

  const int tid = threadIdx.x;
  const int gtid = blockIdx.x * NTHR + tid;
  const int GSZ = NBLK * NTHR;
  unsigned mygen = 0;

  // ---------- Stage A ----------
  // block 0: partitionable-threefry gumbel table + victim scan (fully block-local)
  // blocks 1..63: counter zeroing, hv0 init, weight folds
  if (blockIdx.x == 0) {
    // jax_threefry_partitionable=True (default since jax 0.4.36):
    // per-element 64-bit counter i -> ctr pair (hi,lo)=(0,i); bits = o0 ^ o1
    for (int i = tid; i < 16256; i += NTHR) {
      unsigned o0, o1; threefry2x32(0u, 42u, 0u, (unsigned)i, o0, o1);
      p.g[i] = gumbel_from_bits(o0 ^ o1);
    }
    __syncthreads();   // same block -> p.g visible to wave 0
    if (tid < 64) {
      int lane = tid;
      bool a0 = true, a1 = true;
      float lsum = 0.f;
      for (int s = 0; s < STEPS; ++s) {
        p.alive[s * 128 + lane] = a0 ? 1 : 0;
        p.alive[s * 128 + 64 + lane] = a1 ? 1 : 0;
        float c = logf(1.0f / (float)(128 - s));     // = vlog for alive nodes
        float g0 = a0 ? (c + p.g[s * 128 + lane]) : -INFINITY;
        float g1 = a1 ? (c + p.g[s * 128 + 64 + lane]) : -INFINITY;
        float bv; int bi;
        if (g0 >= g1) { bv = g0; bi = lane; } else { bv = g1; bi = lane + 64; }
        for (int off = 32; off > 0; off >>= 1) {
          float ov = __shfl_down(bv, off);
          int   oi = __shfl_down(bi, off);
          if (ov > bv || (ov == bv && oi < bi)) { bv = ov; bi = oi; }
        }
        int victim = __shfl(bi, 0);
        if (victim == lane) a0 = false;
        if (victim == lane + 64) a1 = false;
        lsum += c;
        if (lane == 0) {
          p.victims[s] = victim;
          p.out[128 + 127 - s] = (float)victim;   // victim_order reversed
        }
      }
      unsigned long long m0 = __ballot(a0), m1 = __ballot(a1);
      int surv = m0 ? (__ffsll(m0) - 1) : (64 + __ffsll(m1) - 1);
      if (lane == 0) { p.misc[0] = surv; p.out[128] = (float)surv; p.out[256] = lsum; }
    }
  } else {
    const int g63 = (blockIdx.x - 1) * NTHR + tid;
    const int GSZ63 = (NBLK - 1) * NTHR;
    for (int i = g63; i < 128; i += GSZ63) { p.in_count[i] = 0; p.cursor[i] = 0; }
    for (int i = g63; i < 16384; i += GSZ63) {
      int v = i >> 7, d = i & 127;
      p.buf0[i] = p.enc_W[d * 32 + p.node_types[v]] + p.enc_b[d];
    }
    // WqT = (Wih@Wa)^T (k-major), WrT = (Wih@Wb)^T
    for (int o = g63; o < 196608; o += GSZ63) {
      int mat = o / 98304; int r = o % 98304; int t = r / 49152; int rr = r % 49152;
      int k = rr / 384, j = rr % 384;
      const float* wih = p.Wih + (size_t)(t * 384 + j) * 128;
      const float* mw  = p.msg_W + (size_t)t * 128 * 272 + (mat * 128 + k);
      float acc = 0.f;
      for (int m = 0; m < 128; ++m) acc += wih[m] * mw[(size_t)m * 272];
      float* dst = (mat == 0 ? p.WqT : p.WrT);
      dst[(size_t)(t * 128 + k) * 384 + j] = acc;
    }
    // W2T = (Wih@We)^T
    for (int o = g63; o < 12288; o += GSZ63) {
      int t = o / 6144; int rr = o % 6144; int k = rr / 384, j = rr % 384;
      const float* wih = p.Wih + (size_t)(t * 384 + j) * 128;
      const float* mw  = p.msg_W + (size_t)t * 128 * 272 + (256 + k);
      float acc = 0.f;
      for (int m = 0; m < 128; ++m) acc += wih[m] * mw[(size_t)m * 272];
      p.W2T[(size_t)(t * 16 + k) * 384 + j] = acc;
    }
    // bm2 = Wih @ msg_b
    for (int o = g63; o < 768; o += GSZ63) {
      int t = o / 384, j = o % 384;
      const float* wih = p.Wih + (size_t)(t * 384 + j) * 128;
      const float* mb = p.msg_b + t * 128;
      float acc = 0.f;
      for (int m = 0; m < 128; ++m) acc += wih[m] * mb[m];
      p.bm2[o] = acc;
    }
    // WhhT transpose (k-major)
    for (int o = g63; o < 98304; o += GSZ63) {
      int t = o / 49152; int rr = o % 49152; int k = rr / 384, j = rr % 384;
      p.WhhT[o] = p.Whh[(size_t)(t * 384 + j) * 128 + k];
    }
  }
  gsync(p.bar, mygen);

  // ---------- Stage B: in-degree histogram (blocks 1..63) ----------
  if (blockIdx.x != 0) {
    for (int e = (blockIdx.x - 1) * NTHR + tid; e < 2048; e += (NBLK - 1) * NTHR)
      atomicAdd(&p.in_count[p.edst[e]], 1);
  }
  gsync(p.bar, mygen);

  // ---------- Stage C: prefix sum of in-degrees (block 0) ----------
  if (blockIdx.x == 0) {
    if (tid < 128) pfs[tid] = p.in_count[tid];
    __syncthreads();
    for (int off = 1; off < 128; off <<= 1) {
      int add = 0;
      if (tid < 128 && tid >= off) add = pfs[tid - off];
      __syncthreads();
      if (tid < 128) pfs[tid] += add;
      __syncthreads();
    }
    if (tid == 0) p.row_ptr[0] = 0;
    if (tid < 128) p.row_ptr[tid + 1] = pfs[tid];
  }
  gsync(p.bar, mygen);

  // ---------- Stage D: CSR scatter ----------
  for (int e = gtid; e < 2048; e += GSZ) {
    int dd = p.edst[e];
    int pos = atomicAdd(&p.cursor[dd], 1);
    int q = p.row_ptr[dd] + pos;
    p.col_src[q] = p.esrc[e];
    p.col_eid[q] = e;
  }
  gsync(p.bar, mygen);

  // ---------- Stage E: per-step deg / HeSum ----------
  for (int i = gtid; i < 16256; i += GSZ) {
    int s = i >> 7, v = i & 127;
    int rp0 = p.row_ptr[v], rp1 = p.row_ptr[v + 1];
    const unsigned char* al = p.alive + s * 128;
    float deg = 0.f; float hacc[16];
    #pragma unroll
    for (int k = 0; k < 16; ++k) hacc[k] = 0.f;
    for (int q = rp0; q < rp1; ++q) {
      int u = p.col_src[q];
      if (al[u]) {
        deg += 1.f;
        const float* hr = p.he + (size_t)p.col_eid[q] * 16;
        #pragma unroll
        for (int k = 0; k < 16; ++k) hacc[k] += hr[k];
      }
    }
    p.degs[i] = deg;
    float* ho = p.HeSum + (size_t)i * 16;
    #pragma unroll
    for (int k = 0; k < 16; ++k) ho[k] = hacc[k];
  }
  gsync(p.bar, mygen);

  // ---------- Stage F: has_edges flags + per-block CSR preload ----------
  for (int s = gtid; s < STEPS; s += GSZ) {
    float acc = 0.f;
    for (int v = 0; v < 128; ++v)
      acc += p.alive[s * 128 + v] ? p.degs[s * 128 + v] : 0.f;
    p.hasE[s] = (acc > 0.f) ? 1 : 0;
  }
  for (int vl = 0; vl < 2; ++vl) {
    int v = blockIdx.x * 2 + vl;
    int rp0 = p.row_ptr[v], rp1 = p.row_ptr[v + 1];
    if (tid == 0) { cntL[vl] = rp1 - rp0; rpL[vl] = rp0; }
    int n = rp1 - rp0; if (n > CAP) n = CAP;
    for (int q = tid; q < n; q += NTHR) colL[vl][q] = p.col_src[rp0 + q];
  }
  gsync(p.bar, mygen);

  // ---------- Main loop: 127 steps x 2 rounds ----------
  const float* cur = p.buf0; float* nxt = p.buf1;
  const int vl = tid >> 7, dd_ = tid & 127;
  const int myv = blockIdx.x * 2 + vl;
  const int wave = tid >> 6, lane6 = tid & 63;
  const int h = wave >> 1;
  const int j0 = (wave & 1) * 64 + lane6;

  for (int s = 0; s < STEPS; ++s) {
    for (int t = 0; t < 2; ++t) {
      // ---- phase 1: stage hv rows, gather S, load per-step scalars ----
      if (tid == 0) { victimL = p.victims[s]; hasEL = p.hasE[s]; }
      if (dd_ == 0) {
        degL[vl] = p.degs[s * 128 + myv];
        aliveL[vl] = p.alive[s * 128 + myv];
      }
      float hvv = cur[(size_t)myv * 128 + dd_];
      hv_lds[vl][dd_] = hvv;
      {
        float acc = 0.f;
        int cnt = cntL[vl];
        int cmin = cnt < CAP ? cnt : CAP;
        int q = 0;
        for (; q + 4 <= cmin; q += 4) {
          int u0 = colL[vl][q], u1 = colL[vl][q + 1], u2 = colL[vl][q + 2], u3 = colL[vl][q + 3];
          float f0 = cur[(size_t)u0 * 128 + dd_];
          float f1 = cur[(size_t)u1 * 128 + dd_];
          float f2 = cur[(size_t)u2 * 128 + dd_];
          float f3 = cur[(size_t)u3 * 128 + dd_];
          acc += f0 + f1 + f2 + f3;
        }
        for (; q < cnt; ++q) {
          int u = (q < CAP) ? colL[vl][q] : p.col_src[rpL[vl] + q];
          acc += cur[(size_t)u * 128 + dd_];
        }
        S_lds[vl][dd_] = acc;
      }
      if (dd_ < 16) He_lds[vl][dd_] = p.HeSum[((size_t)s * 128 + myv) * 16 + dd_];
      __syncthreads();

      // ---- phase 2: gi/gh partials, (j, K-half) split over 4 waves ----
      float accQ[3][2] = {{0.f,0.f},{0.f,0.f},{0.f,0.f}};
      float accR[3][2] = {{0.f,0.f},{0.f,0.f},{0.f,0.f}};
      float accH[3][2] = {{0.f,0.f},{0.f,0.f},{0.f,0.f}};
      for (int kk = 0; kk < 64; kk += 4) {
        int k = h * 64 + kk;
        float4 s0 = *(const float4*)&S_lds[0][k];
        float4 s1 = *(const float4*)&S_lds[1][k];
        float4 x0 = *(const float4*)&hv_lds[0][k];
        float4 x1 = *(const float4*)&hv_lds[1][k];
        float sv0[4] = {s0.x, s0.y, s0.z, s0.w};
        float sv1[4] = {s1.x, s1.y, s1.z, s1.w};
        float xv0[4] = {x0.x, x0.y, x0.z, x0.w};
        float xv1[4] = {x1.x, x1.y, x1.z, x1.w};
        const float* wq = p.WqT + (size_t)(t * 128 + k) * 384;
        const float* wr = p.WrT + (size_t)(t * 128 + k) * 384;
        const float* wh = p.WhhT + (size_t)(t * 128 + k) * 384;
        #pragma unroll
        for (int u = 0; u < 4; ++u) {
          #pragma unroll
          for (int cc = 0; cc < 3; ++cc) {
            float wq_ = wq[u * 384 + j0 + cc * 128];
            float wr_ = wr[u * 384 + j0 + cc * 128];
            float wh_ = wh[u * 384 + j0 + cc * 128];
            accQ[cc][0] += sv0[u] * wq_; accQ[cc][1] += sv1[u] * wq_;
            accR[cc][0] += xv0[u] * wr_; accR[cc][1] += xv1[u] * wr_;
            accH[cc][0] += xv0[u] * wh_; accH[cc][1] += xv1[u] * wh_;
          }
        }
      }
      {
        float deg0 = degL[0], deg1 = degL[1];
        #pragma unroll
        for (int cc = 0; cc < 3; ++cc) {
          int j = j0 + cc * 128;
          float gi0 = accQ[cc][0] + deg0 * accR[cc][0];
          float gi1 = accQ[cc][1] + deg1 * accR[cc][1];
          float gh0 = accH[cc][0], gh1 = accH[cc][1];
          if (h == 0) {
            float ha0 = 0.f, ha1 = 0.f;
            #pragma unroll
            for (int k2 = 0; k2 < 16; ++k2) {
              float w2 = p.W2T[(size_t)(t * 16 + k2) * 384 + j];
              ha0 += He_lds[0][k2] * w2; ha1 += He_lds[1][k2] * w2;
            }
            float bi = p.bih[t * 384 + j], bm = p.bm2[t * 384 + j], bh = p.bhh[t * 384 + j];
            gi0 += ha0 + bi + deg0 * bm; gi1 += ha1 + bi + deg1 * bm;
            gh0 += bh; gh1 += bh;
          }
          pgi[0 * 768 + j * 2 + h] = gi0; pgi[1 * 768 + j * 2 + h] = gi1;
          pgh[0 * 768 + j * 2 + h] = gh0; pgh[1 * 768 + j * 2 + h] = gh1;
        }
      }
      __syncthreads();

      // ---- gates + hv update ----
      {
        int base = vl * 768;
        float gir = pgi[base + dd_ * 2] + pgi[base + dd_ * 2 + 1];
        float giz = pgi[base + (128 + dd_) * 2] + pgi[base + (128 + dd_) * 2 + 1];
        float gin = pgi[base + (256 + dd_) * 2] + pgi[base + (256 + dd_) * 2 + 1];
        float ghr = pgh[base + dd_ * 2] + pgh[base + dd_ * 2 + 1];
        float ghz = pgh[base + (128 + dd_) * 2] + pgh[base + (128 + dd_) * 2 + 1];
        float ghn = pgh[base + (256 + dd_) * 2] + pgh[base + (256 + dd_) * 2 + 1];
        float r = 1.f / (1.f + expf(-(gir + ghr)));
        float z = 1.f / (1.f + expf(-(giz + ghz)));
        float n = tanhf(gin + r * ghn);
        float old = hv_lds[vl][dd_];
        bool upd = (hasEL != 0) && (aliveL[vl] != 0);
        float nv = upd ? (1.f - z) * n + z * old : old;
        if (t == 1 && myv == victimL) nv = 0.f;   // zero dead row so S needs no mask
        nxt[(size_t)myv * 128 + dd_] = nv;
      }
      gsync(p.bar, mygen);
      const float* tmp = nxt; nxt = (float*)cur; cur = tmp;
    }
  }

  // ---------- Epilogue ----------
  if (blockIdx.x == 0 && tid < 128) {
    int surv = p.misc[0];
    p.out[tid] = cur[(size_t)surv * 128 + tid];
  }
}

extern "C" void kernel_launch(void* const* d_in, const int* in_sizes, int n_in,
                              void* d_out, int out_size, void* d_ws, size_t ws_size,
                              hipStream_t stream) {
  (void)in_sizes; (void)n_in; (void)out_size; (void)ws_size;
  GDParams p;
  p.node_types = (const int*)d_in[0];
  p.esrc = (const int*)d_in[1];
  p.edst = (const int*)d_in[2];
  p.he   = (const float*)d_in[3];
  p.enc_W = (const float*)d_in[4];
  p.enc_b = (const float*)d_in[5];
  p.msg_W = (const float*)d_in[6];
  p.msg_b = (const float*)d_in[7];
  p.Wih = (const float*)d_in[8];
  p.Whh = (const float*)d_in[9];
  p.bih = (const float*)d_in[10];
  p.bhh = (const float*)d_in[11];

  char* w = (char*)d_ws;
  auto take = [&](size_t n) { char* r = w; w += (n + 255) & ~(size_t)255; return r; };
  p.bar   = (unsigned*)take(256);
  p.buf0  = (float*)take(16384 * 4);
  p.buf1  = (float*)take(16384 * 4);
  p.g     = (float*)take(16256 * 4);
  p.WqT   = (float*)take(98304 * 4);
  p.WrT   = (float*)take(98304 * 4);
  p.WhhT  = (float*)take(98304 * 4);
  p.W2T   = (float*)take(12288 * 4);
  p.bm2   = (float*)take(768 * 4);
  p.HeSum = (float*)take((size_t)16256 * 16 * 4);
  p.degs  = (float*)take(16256 * 4);
  p.alive = (unsigned char*)take(16384);
  p.hasE  = (unsigned char*)take(256);
  p.victims  = (int*)take(STEPS * 4);
  p.row_ptr  = (int*)take(129 * 4);
  p.in_count = (int*)take(128 * 4);
  p.cursor   = (int*)take(128 * 4);
  p.col_src  = (int*)take(2048 * 4);
  p.col_eid  = (int*)take(2048 * 4);
  p.misc     = (int*)take(256);
  p.out = (float*)d_out;

  hipMemsetAsync(p.bar, 0, 256, stream);   // barrier state must start at 0 (ws is poisoned)
  void* args[] = { (void*)&p };
  hipError_t err = hipLaunchCooperativeKernel(reinterpret_cast<void*>(gd_main),
                                              dim3(NBLK), dim3(NTHR), args, 0, stream);
  if (err != hipSuccess) {
    // fallback: 64 blocks trivially co-resident on 256 CUs
    hipLaunchKernelGGL(gd_main, dim3(NBLK), dim3(NTHR), 0, stream, p);
  }
}

// Round 4
// 4179.214 us; speedup vs baseline: 1.0390x; 1.0390x over previous
//
#include <hip/hip_runtime.h>
#include <math.h>
#include <stdint.h>

#define STEPS 127
#define NBLK 32
#define NTHR 512
#define CAP 160

struct GDParams {
  const int* node_types; const int* esrc; const int* edst; const float* he;
  const float* enc_W; const float* enc_b; const float* msg_W; const float* msg_b;
  const float* Wih; const float* Whh; const float* bih; const float* bhh;
  unsigned* bar;          // [0]=counter [1]=generation (setup barrier)
  unsigned* slots;        // [NBLK] per-block round slots (fast barrier)
  float* buf0; float* buf1;
  float* g;               // 16256 gumbel values
  float* WqT; float* WrT; float* WhhT;   // [2][128][384] k-major folded weights
  float* W2T;             // [2][16][384]
  float* bm2;             // [2][384]
  float* HeSum;           // [127][128][16]
  float* degs;            // [127][128]
  unsigned char* alive;   // [127][128]
  unsigned char* hasE;    // [127]
  int* victims; int* row_ptr; int* in_count; int* cursor; int* col_src; int* col_eid;
  int* misc;              // [0] = survivor
  float* out;             // 257 floats: hv[surv](128) | victim_order(128) | logps(1)
};

__device__ __forceinline__ void tfround(unsigned &x0, unsigned &x1, int r) {
  x0 += x1; x1 = (x1 << r) | (x1 >> (32 - r)); x1 ^= x0;
}
__device__ void threefry2x32(unsigned k0, unsigned k1, unsigned c0, unsigned c1,
                             unsigned &o0, unsigned &o1) {
  unsigned ks2 = k0 ^ k1 ^ 0x1BD11BDAu;
  unsigned x0 = c0 + k0, x1 = c1 + k1;
  tfround(x0,x1,13); tfround(x0,x1,15); tfround(x0,x1,26); tfround(x0,x1,6);
  x0 += k1; x1 += ks2 + 1u;
  tfround(x0,x1,17); tfround(x0,x1,29); tfround(x0,x1,16); tfround(x0,x1,24);
  x0 += ks2; x1 += k0 + 2u;
  tfround(x0,x1,13); tfround(x0,x1,15); tfround(x0,x1,26); tfround(x0,x1,6);
  x0 += k0; x1 += k1 + 3u;
  tfround(x0,x1,17); tfround(x0,x1,29); tfround(x0,x1,16); tfround(x0,x1,24);
  x0 += k1; x1 += ks2 + 4u;
  tfround(x0,x1,13); tfround(x0,x1,15); tfround(x0,x1,26); tfround(x0,x1,6);
  x0 += ks2; x1 += k0 + 5u;
  o0 = x0; o1 = x1;
}
__device__ __forceinline__ float gumbel_from_bits(unsigned b) {
  unsigned fb = (b >> 9) | 0x3F800000u;
  float f = __uint_as_float(fb) - 1.0f;
  const float tiny = 1.17549435e-38f;
  float u = fmaxf(tiny, f * (1.0f - tiny) + tiny);
  return -logf(-logf(u));
}

// sc1 (agent-coherent) data path — no cache maintenance ops
__device__ __forceinline__ float ld_dev(const float* a) {
  return __hip_atomic_load(const_cast<float*>(a), __ATOMIC_RELAXED, __HIP_MEMORY_SCOPE_AGENT);
}
__device__ __forceinline__ void st_dev(float* a, float v) {
  __hip_atomic_store(a, v, __ATOMIC_RELAXED, __HIP_MEMORY_SCOPE_AGENT);
}

// heavyweight setup barrier (acq/rel; also publishes plain-written setup data)
__device__ __forceinline__ void gsync(unsigned* bar, unsigned &mygen) {
  __syncthreads();
  mygen++;
  if (threadIdx.x == 0) {
    unsigned prev = __hip_atomic_fetch_add(&bar[0], 1u, __ATOMIC_ACQ_REL, __HIP_MEMORY_SCOPE_AGENT);
    if (prev == (unsigned)(gridDim.x - 1u)) {
      __hip_atomic_store(&bar[0], 0u, __ATOMIC_RELAXED, __HIP_MEMORY_SCOPE_AGENT);
      __hip_atomic_store(&bar[1], mygen, __ATOMIC_RELEASE, __HIP_MEMORY_SCOPE_AGENT);
    } else {
      long guard = 0;
      while (__hip_atomic_load(&bar[1], __ATOMIC_ACQUIRE, __HIP_MEMORY_SCOPE_AGENT) != mygen) {
        if (++guard > (1L << 30)) break;
      }
    }
  }
  __syncthreads();
}

// fast barrier: no RMW, no cache ops. __syncthreads drains vmcnt (sc1 stores
// are then globally visible), each block posts its slot, wave0 polls all slots.
__device__ __forceinline__ void fastbar(unsigned* slots, unsigned r) {
  __syncthreads();   // drains every thread's vmcnt -> hv sc1-stores visible
  if (threadIdx.x == 0)
    __hip_atomic_store(&slots[blockIdx.x], r, __ATOMIC_RELAXED, __HIP_MEMORY_SCOPE_AGENT);
  if (threadIdx.x < 64) {
    int lane = threadIdx.x;
    long guard = 0;
    for (;;) {
      unsigned v = (lane < NBLK)
        ? __hip_atomic_load(&slots[lane], __ATOMIC_RELAXED, __HIP_MEMORY_SCOPE_AGENT)
        : 0xFFFFFFFFu;
      if (__all(v >= r)) break;
      if (++guard > (1L << 22)) break;   // safety valve
    }
  }
  // workgroup-scope fence: compiler ordering only, no cache-maintenance ops on CDNA
  __builtin_amdgcn_fence(__ATOMIC_ACQUIRE, "workgroup");
  __syncthreads();
}

__global__ __launch_bounds__(NTHR, 1) void gd_main(GDParams p) {
  __shared__ alignas(16) float S_lds[4][128];
  __shared__ alignas(16) float hv_lds[4][128];
  __shared__ float He_lds[4][16];
  __shared__ float pgi[3072];   // [v][384][h]
  __shared__ float pgh[3072];
  __shared__ int colL[4][CAP];
  __shared__ int cntL[4]; __shared__ int rpL[4];
  __shared__ float degL[4]; __shared__ int aliveL[4];
  __shared__ int victimL; __shared__ int hasEL;
  __shared__ int pfs[128];

  const int tid = threadIdx.x;
  const int gtid = blockIdx.x * NTHR + tid;
  const int GSZ = NBLK * NTHR;
  unsigned mygen = 0;

  // ---------- Stage A ----------
  if (blockIdx.x == 0) {
    // jax_threefry_partitionable (default since 0.4.36): ctr=(0,i), bits=o0^o1
    for (int i = tid; i < 16256; i += NTHR) {
      unsigned o0, o1; threefry2x32(0u, 42u, 0u, (unsigned)i, o0, o1);
      p.g[i] = gumbel_from_bits(o0 ^ o1);
    }
    __syncthreads();
    if (tid < 64) {
      int lane = tid;
      bool a0 = true, a1 = true;
      float lsum = 0.f;
      for (int s = 0; s < STEPS; ++s) {
        p.alive[s * 128 + lane] = a0 ? 1 : 0;
        p.alive[s * 128 + 64 + lane] = a1 ? 1 : 0;
        float c = logf(1.0f / (float)(128 - s));
        float g0 = a0 ? (c + p.g[s * 128 + lane]) : -INFINITY;
        float g1 = a1 ? (c + p.g[s * 128 + 64 + lane]) : -INFINITY;
        float bv; int bi;
        if (g0 >= g1) { bv = g0; bi = lane; } else { bv = g1; bi = lane + 64; }
        for (int off = 32; off > 0; off >>= 1) {
          float ov = __shfl_down(bv, off);
          int   oi = __shfl_down(bi, off);
          if (ov > bv || (ov == bv && oi < bi)) { bv = ov; bi = oi; }
        }
        int victim = __shfl(bi, 0);
        if (victim == lane) a0 = false;
        if (victim == lane + 64) a1 = false;
        lsum += c;
        if (lane == 0) {
          p.victims[s] = victim;
          p.out[128 + 127 - s] = (float)victim;
        }
      }
      unsigned long long m0 = __ballot(a0), m1 = __ballot(a1);
      int surv = m0 ? (__ffsll(m0) - 1) : (64 + __ffsll(m1) - 1);
      if (lane == 0) { p.misc[0] = surv; p.out[128] = (float)surv; p.out[256] = lsum; }
    }
  } else {
    const int g63 = (blockIdx.x - 1) * NTHR + tid;
    const int GSZ63 = (NBLK - 1) * NTHR;
    for (int i = g63; i < 128; i += GSZ63) { p.in_count[i] = 0; p.cursor[i] = 0; }
    for (int i = g63; i < 16384; i += GSZ63) {
      int v = i >> 7, d = i & 127;
      p.buf0[i] = p.enc_W[d * 32 + p.node_types[v]] + p.enc_b[d];
    }
    for (int o = g63; o < 196608; o += GSZ63) {
      int mat = o / 98304; int r = o % 98304; int t = r / 49152; int rr = r % 49152;
      int k = rr / 384, j = rr % 384;
      const float* wih = p.Wih + (size_t)(t * 384 + j) * 128;
      const float* mw  = p.msg_W + (size_t)t * 128 * 272 + (mat * 128 + k);
      float acc = 0.f;
      for (int m = 0; m < 128; ++m) acc += wih[m] * mw[(size_t)m * 272];
      float* dst = (mat == 0 ? p.WqT : p.WrT);
      dst[(size_t)(t * 128 + k) * 384 + j] = acc;
    }
    for (int o = g63; o < 12288; o += GSZ63) {
      int t = o / 6144; int rr = o % 6144; int k = rr / 384, j = rr % 384;
      const float* wih = p.Wih + (size_t)(t * 384 + j) * 128;
      const float* mw  = p.msg_W + (size_t)t * 128 * 272 + (256 + k);
      float acc = 0.f;
      for (int m = 0; m < 128; ++m) acc += wih[m] * mw[(size_t)m * 272];
      p.W2T[(size_t)(t * 16 + k) * 384 + j] = acc;
    }
    for (int o = g63; o < 768; o += GSZ63) {
      int t = o / 384, j = o % 384;
      const float* wih = p.Wih + (size_t)(t * 384 + j) * 128;
      const float* mb = p.msg_b + t * 128;
      float acc = 0.f;
      for (int m = 0; m < 128; ++m) acc += wih[m] * mb[m];
      p.bm2[o] = acc;
    }
    for (int o = g63; o < 98304; o += GSZ63) {
      int t = o / 49152; int rr = o % 49152; int k = rr / 384, j = rr % 384;
      p.WhhT[o] = p.Whh[(size_t)(t * 384 + j) * 128 + k];
    }
  }
  gsync(p.bar, mygen);

  // ---------- Stage B: in-degree histogram ----------
  if (blockIdx.x != 0) {
    for (int e = (blockIdx.x - 1) * NTHR + tid; e < 2048; e += (NBLK - 1) * NTHR)
      atomicAdd(&p.in_count[p.edst[e]], 1);
  }
  gsync(p.bar, mygen);

  // ---------- Stage C: prefix sum (block 0) ----------
  if (blockIdx.x == 0) {
    if (tid < 128) pfs[tid] = p.in_count[tid];
    __syncthreads();
    for (int off = 1; off < 128; off <<= 1) {
      int add = 0;
      if (tid < 128 && tid >= off) add = pfs[tid - off];
      __syncthreads();
      if (tid < 128) pfs[tid] += add;
      __syncthreads();
    }
    if (tid == 0) p.row_ptr[0] = 0;
    if (tid < 128) p.row_ptr[tid + 1] = pfs[tid];
  }
  gsync(p.bar, mygen);

  // ---------- Stage D: CSR scatter ----------
  for (int e = gtid; e < 2048; e += GSZ) {
    int dd = p.edst[e];
    int pos = atomicAdd(&p.cursor[dd], 1);
    int q = p.row_ptr[dd] + pos;
    p.col_src[q] = p.esrc[e];
    p.col_eid[q] = e;
  }
  gsync(p.bar, mygen);

  // ---------- Stage E: per-step deg / HeSum ----------
  for (int i = gtid; i < 16256; i += GSZ) {
    int s = i >> 7, v = i & 127;
    int rp0 = p.row_ptr[v], rp1 = p.row_ptr[v + 1];
    const unsigned char* al = p.alive + s * 128;
    float deg = 0.f; float hacc[16];
    #pragma unroll
    for (int k = 0; k < 16; ++k) hacc[k] = 0.f;
    for (int q = rp0; q < rp1; ++q) {
      int u = p.col_src[q];
      if (al[u]) {
        deg += 1.f;
        const float* hr = p.he + (size_t)p.col_eid[q] * 16;
        #pragma unroll
        for (int k = 0; k < 16; ++k) hacc[k] += hr[k];
      }
    }
    p.degs[i] = deg;
    float* ho = p.HeSum + (size_t)i * 16;
    #pragma unroll
    for (int k = 0; k < 16; ++k) ho[k] = hacc[k];
  }
  gsync(p.bar, mygen);

  // ---------- Stage F: has_edges + per-block CSR preload ----------
  for (int s = gtid; s < STEPS; s += GSZ) {
    float acc = 0.f;
    for (int v = 0; v < 128; ++v)
      acc += p.alive[s * 128 + v] ? p.degs[s * 128 + v] : 0.f;
    p.hasE[s] = (acc > 0.f) ? 1 : 0;
  }
  for (int vv = 0; vv < 4; ++vv) {
    int v = blockIdx.x * 4 + vv;
    int rp0 = p.row_ptr[v], rp1 = p.row_ptr[v + 1];
    if (tid == 0) { cntL[vv] = rp1 - rp0; rpL[vv] = rp0; }
    int n = rp1 - rp0; if (n > CAP) n = CAP;
    for (int q = tid; q < n; q += NTHR) colL[vv][q] = p.col_src[rp0 + q];
  }
  gsync(p.bar, mygen);   // also publishes all setup data (wbl2) for sc1 readers

  // ---------- Main loop: 127 steps x 2 rounds, fast barrier ----------
  const float* cur = p.buf0; float* nxt = p.buf1;
  const int vl = tid >> 7, dd_ = tid & 127;       // (node, dim)
  const int myv = blockIdx.x * 4 + vl;
  const int wave = tid >> 6, lane6 = tid & 63;
  const int np = wave >> 2;                        // node-pair 0/1
  const int h = (wave >> 1) & 1;                   // K-half
  const int j0 = (wave & 1) * 64 + lane6;          // j within [0,128)

  hv_lds[vl][dd_] = p.buf0[(size_t)myv * 128 + dd_];   // own rows live in LDS

  unsigned r = 0;
  for (int s = 0; s < STEPS; ++s) {
    for (int t = 0; t < 2; ++t) {
      r++;
      // ---- phase 1: gather S via sc1 loads; per-step scalars ----
      if (tid == 0) { victimL = p.victims[s]; hasEL = p.hasE[s]; }
      if (dd_ == 0) {
        degL[vl] = p.degs[s * 128 + myv];
        aliveL[vl] = p.alive[s * 128 + myv];
      }
      {
        float acc = 0.f;
        int cnt = cntL[vl];
        int cmin = cnt < CAP ? cnt : CAP;
        int q = 0;
        for (; q + 8 <= cmin; q += 8) {
          int u0 = colL[vl][q],   u1 = colL[vl][q+1], u2 = colL[vl][q+2], u3 = colL[vl][q+3];
          int u4 = colL[vl][q+4], u5 = colL[vl][q+5], u6 = colL[vl][q+6], u7 = colL[vl][q+7];
          float f0 = ld_dev(&cur[(size_t)u0*128 + dd_]);
          float f1 = ld_dev(&cur[(size_t)u1*128 + dd_]);
          float f2 = ld_dev(&cur[(size_t)u2*128 + dd_]);
          float f3 = ld_dev(&cur[(size_t)u3*128 + dd_]);
          float f4 = ld_dev(&cur[(size_t)u4*128 + dd_]);
          float f5 = ld_dev(&cur[(size_t)u5*128 + dd_]);
          float f6 = ld_dev(&cur[(size_t)u6*128 + dd_]);
          float f7 = ld_dev(&cur[(size_t)u7*128 + dd_]);
          acc += ((f0+f1)+(f2+f3)) + ((f4+f5)+(f6+f7));
        }
        for (; q < cnt; ++q) {
          int u = (q < CAP) ? colL[vl][q] : p.col_src[rpL[vl] + q];
          acc += ld_dev(&cur[(size_t)u*128 + dd_]);
        }
        S_lds[vl][dd_] = acc;
      }
      if (dd_ < 16) He_lds[vl][dd_] = p.HeSum[((size_t)s * 128 + myv) * 16 + dd_];
      __syncthreads();

      // ---- phase 2: gi/gh partials; waves split (np, K-half, j-half) ----
      float accQ[3][2] = {{0.f,0.f},{0.f,0.f},{0.f,0.f}};
      float accR[3][2] = {{0.f,0.f},{0.f,0.f},{0.f,0.f}};
      float accH[3][2] = {{0.f,0.f},{0.f,0.f},{0.f,0.f}};
      for (int kk = 0; kk < 64; kk += 4) {
        int k = h * 64 + kk;
        float4 s0 = *(const float4*)&S_lds[np*2+0][k];
        float4 s1 = *(const float4*)&S_lds[np*2+1][k];
        float4 x0 = *(const float4*)&hv_lds[np*2+0][k];
        float4 x1 = *(const float4*)&hv_lds[np*2+1][k];
        float sv0[4] = {s0.x, s0.y, s0.z, s0.w};
        float sv1[4] = {s1.x, s1.y, s1.z, s1.w};
        float xv0[4] = {x0.x, x0.y, x0.z, x0.w};
        float xv1[4] = {x1.x, x1.y, x1.z, x1.w};
        const float* wq = p.WqT + (size_t)(t * 128 + k) * 384;
        const float* wr = p.WrT + (size_t)(t * 128 + k) * 384;
        const float* wh = p.WhhT + (size_t)(t * 128 + k) * 384;
        #pragma unroll
        for (int u = 0; u < 4; ++u) {
          #pragma unroll
          for (int cc = 0; cc < 3; ++cc) {
            float wq_ = wq[u * 384 + j0 + cc * 128];
            float wr_ = wr[u * 384 + j0 + cc * 128];
            float wh_ = wh[u * 384 + j0 + cc * 128];
            accQ[cc][0] += sv0[u] * wq_; accQ[cc][1] += sv1[u] * wq_;
            accR[cc][0] += xv0[u] * wr_; accR[cc][1] += xv1[u] * wr_;
            accH[cc][0] += xv0[u] * wh_; accH[cc][1] += xv1[u] * wh_;
          }
        }
      }
      {
        float deg0 = degL[np*2+0], deg1 = degL[np*2+1];
        #pragma unroll
        for (int cc = 0; cc < 3; ++cc) {
          int j = j0 + cc * 128;
          float gi0 = accQ[cc][0] + deg0 * accR[cc][0];
          float gi1 = accQ[cc][1] + deg1 * accR[cc][1];
          float gh0 = accH[cc][0], gh1 = accH[cc][1];
          if (h == 0) {
            float ha0 = 0.f, ha1 = 0.f;
            #pragma unroll
            for (int k2 = 0; k2 < 16; ++k2) {
              float w2 = p.W2T[(size_t)(t * 16 + k2) * 384 + j];
              ha0 += He_lds[np*2+0][k2] * w2; ha1 += He_lds[np*2+1][k2] * w2;
            }
            float bi = p.bih[t * 384 + j], bm = p.bm2[t * 384 + j], bh = p.bhh[t * 384 + j];
            gi0 += ha0 + bi + deg0 * bm; gi1 += ha1 + bi + deg1 * bm;
            gh0 += bh; gh1 += bh;
          }
          pgi[((np*2+0) * 384 + j) * 2 + h] = gi0; pgi[((np*2+1) * 384 + j) * 2 + h] = gi1;
          pgh[((np*2+0) * 384 + j) * 2 + h] = gh0; pgh[((np*2+1) * 384 + j) * 2 + h] = gh1;
        }
      }
      __syncthreads();

      // ---- gates + hv update (sc1 store) ----
      {
        int base = vl * 768;
        float gir = pgi[base + dd_ * 2] + pgi[base + dd_ * 2 + 1];
        float giz = pgi[base + (128 + dd_) * 2] + pgi[base + (128 + dd_) * 2 + 1];
        float gin = pgi[base + (256 + dd_) * 2] + pgi[base + (256 + dd_) * 2 + 1];
        float ghr = pgh[base + dd_ * 2] + pgh[base + dd_ * 2 + 1];
        float ghz = pgh[base + (128 + dd_) * 2] + pgh[base + (128 + dd_) * 2 + 1];
        float ghn = pgh[base + (256 + dd_) * 2] + pgh[base + (256 + dd_) * 2 + 1];
        float rr_ = 1.f / (1.f + expf(-(gir + ghr)));
        float z = 1.f / (1.f + expf(-(giz + ghz)));
        float n = tanhf(gin + rr_ * ghn);
        float old = hv_lds[vl][dd_];
        bool upd = (hasEL != 0) && (aliveL[vl] != 0);
        float nv = upd ? (1.f - z) * n + z * old : old;
        if (t == 1 && myv == victimL) nv = 0.f;
        st_dev(&nxt[(size_t)myv * 128 + dd_], nv);
        hv_lds[vl][dd_] = nv;
      }
      fastbar(p.slots, r);
      const float* tmp = nxt; nxt = (float*)cur; cur = tmp;
    }
  }

  // ---------- Epilogue ----------
  if (blockIdx.x == 0 && tid < 128) {
    int surv = p.misc[0];
    p.out[tid] = ld_dev(&cur[(size_t)surv * 128 + tid]);
  }
}

extern "C" void kernel_launch(void* const* d_in, const int* in_sizes, int n_in,
                              void* d_out, int out_size, void* d_ws, size_t ws_size,
                              hipStream_t stream) {
  (void)in_sizes; (void)n_in; (void)out_size; (void)ws_size;
  GDParams p;
  p.node_types = (const int*)d_in[0];
  p.esrc = (const int*)d_in[1];
  p.edst = (const int*)d_in[2];
  p.he   = (const float*)d_in[3];
  p.enc_W = (const float*)d_in[4];
  p.enc_b = (const float*)d_in[5];
  p.msg_W = (const float*)d_in[6];
  p.msg_b = (const float*)d_in[7];
  p.Wih = (const float*)d_in[8];
  p.Whh = (const float*)d_in[9];
  p.bih = (const float*)d_in[10];
  p.bhh = (const float*)d_in[11];

  char* w = (char*)d_ws;
  auto take = [&](size_t n) { char* r = w; w += (n + 255) & ~(size_t)255; return r; };
  p.bar   = (unsigned*)take(256);
  p.slots = (unsigned*)take(256);
  p.buf0  = (float*)take(16384 * 4);
  p.buf1  = (float*)take(16384 * 4);
  p.g     = (float*)take(16256 * 4);
  p.WqT   = (float*)take(98304 * 4);
  p.WrT   = (float*)take(98304 * 4);
  p.WhhT  = (float*)take(98304 * 4);
  p.W2T   = (float*)take(12288 * 4);
  p.bm2   = (float*)take(768 * 4);
  p.HeSum = (float*)take((size_t)16256 * 16 * 4);
  p.degs  = (float*)take(16256 * 4);
  p.alive = (unsigned char*)take(16384);
  p.hasE  = (unsigned char*)take(256);
  p.victims  = (int*)take(STEPS * 4);
  p.row_ptr  = (int*)take(129 * 4);
  p.in_count = (int*)take(128 * 4);
  p.cursor   = (int*)take(128 * 4);
  p.col_src  = (int*)take(2048 * 4);
  p.col_eid  = (int*)take(2048 * 4);
  p.misc     = (int*)take(256);
  p.out = (float*)d_out;

  (void)hipMemsetAsync(p.bar, 0, 512, stream);   // bar + slots must start at 0
  void* args[] = { (void*)&p };
  hipError_t err = hipLaunchCooperativeKernel(reinterpret_cast<void*>(gd_main),
                                              dim3(NBLK), dim3(NTHR), args, 0, stream);
  if (err != hipSuccess) {
    hipLaunchKernelGGL(gd_main, dim3(NBLK), dim3(NTHR), 0, stream, p);
  }
}

// Round 5
// 3006.464 us; speedup vs baseline: 1.4443x; 1.3901x over previous
//
#include <hip/hip_runtime.h>
#include <math.h>
#include <stdint.h>

#define STEPS 127
#define NBLK 64
#define NTHR 512
#define CAP 160

typedef unsigned int uint;

struct GDParams {
  const int* node_types; const int* esrc; const int* edst; const float* he;
  const float* enc_W; const float* enc_b; const float* msg_W; const float* msg_b;
  const float* Wih; const float* Whh; const float* bih; const float* bhh;
  unsigned* bar;          // [0]=counter [1]=generation (setup barrier)
  unsigned* slots;        // [NBLK] per-block round slots (fast barrier)
  float* buf0; float* buf1;
  float* g;               // 16256 gumbel values
  unsigned short* Wp;     // bf16 packed weights [mt(6)][kc(16)][j(384)][8k]
  float* W2T;             // [2][16][384] f32
  float* bm2;             // [2][384]
  float* HeSum;           // [127][128][16]
  float* degs;            // [127][128]
  unsigned char* alive;   // [127][128]
  unsigned char* hasE;    // [127]
  int* victims; int* row_ptr; int* in_count; int* cursor; int* col_src; int* col_eid;
  int* misc;              // [0] = survivor
  float* out;             // 257 floats: hv[surv](128) | victim_order(128) | logps(1)
};

__device__ __forceinline__ void tfround(unsigned &x0, unsigned &x1, int r) {
  x0 += x1; x1 = (x1 << r) | (x1 >> (32 - r)); x1 ^= x0;
}
__device__ void threefry2x32(unsigned k0, unsigned k1, unsigned c0, unsigned c1,
                             unsigned &o0, unsigned &o1) {
  unsigned ks2 = k0 ^ k1 ^ 0x1BD11BDAu;
  unsigned x0 = c0 + k0, x1 = c1 + k1;
  tfround(x0,x1,13); tfround(x0,x1,15); tfround(x0,x1,26); tfround(x0,x1,6);
  x0 += k1; x1 += ks2 + 1u;
  tfround(x0,x1,17); tfround(x0,x1,29); tfround(x0,x1,16); tfround(x0,x1,24);
  x0 += ks2; x1 += k0 + 2u;
  tfround(x0,x1,13); tfround(x0,x1,15); tfround(x0,x1,26); tfround(x0,x1,6);
  x0 += k0; x1 += k1 + 3u;
  tfround(x0,x1,17); tfround(x0,x1,29); tfround(x0,x1,16); tfround(x0,x1,24);
  x0 += k1; x1 += ks2 + 4u;
  tfround(x0,x1,13); tfround(x0,x1,15); tfround(x0,x1,26); tfround(x0,x1,6);
  x0 += ks2; x1 += k0 + 5u;
  o0 = x0; o1 = x1;
}
__device__ __forceinline__ float gumbel_from_bits(unsigned b) {
  unsigned fb = (b >> 9) | 0x3F800000u;
  float f = __uint_as_float(fb) - 1.0f;
  const float tiny = 1.17549435e-38f;
  float u = fmaxf(tiny, f * (1.0f - tiny) + tiny);
  return -logf(-logf(u));
}

__device__ __forceinline__ unsigned short f2bf(float f) {
  unsigned u = __float_as_uint(f);
  unsigned r = (u + 0x7FFFu + ((u >> 16) & 1u)) >> 16;
  return (unsigned short)r;
}

#if __has_builtin(__builtin_amdgcn_fdot2_f32_bf16)
typedef __bf16 bf2 __attribute__((ext_vector_type(2)));
__device__ __forceinline__ float dot2bf(uint a, uint b, float c) {
  return __builtin_amdgcn_fdot2_f32_bf16(__builtin_bit_cast(bf2, a),
                                         __builtin_bit_cast(bf2, b), c, false);
}
#else
__device__ __forceinline__ float dot2bf(uint a, uint b, float c) {
  float a0 = __uint_as_float(a << 16), a1 = __uint_as_float(a & 0xFFFF0000u);
  float b0 = __uint_as_float(b << 16), b1 = __uint_as_float(b & 0xFFFF0000u);
  return fmaf(a0, b0, fmaf(a1, b1, c));
}
#endif

// sc1 (agent-coherent) data path
__device__ __forceinline__ float ld_dev(const float* a) {
  return __hip_atomic_load(const_cast<float*>(a), __ATOMIC_RELAXED, __HIP_MEMORY_SCOPE_AGENT);
}
__device__ __forceinline__ void st_dev(float* a, float v) {
  __hip_atomic_store(a, v, __ATOMIC_RELAXED, __HIP_MEMORY_SCOPE_AGENT);
}

// heavyweight setup barrier (acq/rel; publishes plain-written setup data)
__device__ __forceinline__ void gsync(unsigned* bar, unsigned &mygen) {
  __syncthreads();
  mygen++;
  if (threadIdx.x == 0) {
    unsigned prev = __hip_atomic_fetch_add(&bar[0], 1u, __ATOMIC_ACQ_REL, __HIP_MEMORY_SCOPE_AGENT);
    if (prev == (unsigned)(gridDim.x - 1u)) {
      __hip_atomic_store(&bar[0], 0u, __ATOMIC_RELAXED, __HIP_MEMORY_SCOPE_AGENT);
      __hip_atomic_store(&bar[1], mygen, __ATOMIC_RELEASE, __HIP_MEMORY_SCOPE_AGENT);
    } else {
      long guard = 0;
      while (__hip_atomic_load(&bar[1], __ATOMIC_ACQUIRE, __HIP_MEMORY_SCOPE_AGENT) != mygen) {
        if (++guard > (1L << 30)) break;
      }
    }
  }
  __syncthreads();
}

// split fast barrier: post (syncthreads drains vmcnt -> hv stores visible, then
// fire-and-forget slot store) ... local-only work ... wait (wave0 polls, all sync)
__device__ __forceinline__ void bpost(unsigned* slots, unsigned r) {
  __syncthreads();
  if (threadIdx.x == 0)
    __hip_atomic_store(&slots[blockIdx.x], r, __ATOMIC_RELAXED, __HIP_MEMORY_SCOPE_AGENT);
}
__device__ __forceinline__ void bwait(unsigned* slots, unsigned r) {
  if (threadIdx.x < 64) {
    long guard = 0;
    for (;;) {
      unsigned v = __hip_atomic_load(&slots[threadIdx.x], __ATOMIC_RELAXED, __HIP_MEMORY_SCOPE_AGENT);
      if (__all(v >= r)) break;
      if (++guard > (1L << 22)) break;   // safety valve
    }
  }
  __builtin_amdgcn_fence(__ATOMIC_ACQUIRE, "workgroup");  // ordering only, no cache ops
  __syncthreads();
}

__global__ __launch_bounds__(NTHR, 1) void gd_main(GDParams p) {
  __shared__ float pgq[4][2][384];            // [kquarter][node][j]
  __shared__ float pgr[2][2][384];            // [khalf][node][j]
  __shared__ float pgh[2][2][384];
  __shared__ float pgHe[2][384];              // He + bih + deg*bm2
  __shared__ alignas(16) unsigned short S_bf[2][128];
  __shared__ alignas(16) unsigned short hv_bf[2][128];
  __shared__ float hv_f[2][128];
  __shared__ int colL[2][CAP];
  __shared__ int cntL[2]; __shared__ int rpL[2];
  __shared__ float degL[2]; __shared__ int aliveL[2];
  __shared__ int victimL; __shared__ int hasEL;
  __shared__ int pfs[128];

  const int tid = threadIdx.x;
  const int gtid = blockIdx.x * NTHR + tid;
  const int GSZ = NBLK * NTHR;
  unsigned mygen = 0;

  // ---------- Stage A ----------
  if (blockIdx.x == 0) {
    // jax_threefry_partitionable (default since 0.4.36): ctr=(0,i), bits=o0^o1
    for (int i = tid; i < 16256; i += NTHR) {
      unsigned o0, o1; threefry2x32(0u, 42u, 0u, (unsigned)i, o0, o1);
      p.g[i] = gumbel_from_bits(o0 ^ o1);
    }
    __syncthreads();
    if (tid < 64) {
      int lane = tid;
      bool a0 = true, a1 = true;
      float lsum = 0.f;
      for (int s = 0; s < STEPS; ++s) {
        p.alive[s * 128 + lane] = a0 ? 1 : 0;
        p.alive[s * 128 + 64 + lane] = a1 ? 1 : 0;
        float c = logf(1.0f / (float)(128 - s));
        float g0 = a0 ? (c + p.g[s * 128 + lane]) : -INFINITY;
        float g1 = a1 ? (c + p.g[s * 128 + 64 + lane]) : -INFINITY;
        float bv; int bi;
        if (g0 >= g1) { bv = g0; bi = lane; } else { bv = g1; bi = lane + 64; }
        for (int off = 32; off > 0; off >>= 1) {
          float ov = __shfl_down(bv, off);
          int   oi = __shfl_down(bi, off);
          if (ov > bv || (ov == bv && oi < bi)) { bv = ov; bi = oi; }
        }
        int victim = __shfl(bi, 0);
        if (victim == lane) a0 = false;
        if (victim == lane + 64) a1 = false;
        lsum += c;
        if (lane == 0) {
          p.victims[s] = victim;
          p.out[128 + 127 - s] = (float)victim;
        }
      }
      unsigned long long m0 = __ballot(a0), m1 = __ballot(a1);
      int surv = m0 ? (__ffsll(m0) - 1) : (64 + __ffsll(m1) - 1);
      if (lane == 0) { p.misc[0] = surv; p.out[128] = (float)surv; p.out[256] = lsum; }
    }
  } else {
    const int g63 = (blockIdx.x - 1) * NTHR + tid;
    const int GSZ63 = (NBLK - 1) * NTHR;
    for (int i = g63; i < 128; i += GSZ63) { p.in_count[i] = 0; p.cursor[i] = 0; }
    for (int i = g63; i < 16384; i += GSZ63) {
      int v = i >> 7, d = i & 127;
      p.buf0[i] = p.enc_W[d * 32 + p.node_types[v]] + p.enc_b[d];
    }
    // folded Wq = Wih@Wa (mat 0), Wr = Wih@Wb (mat 1) -> bf16 packed layout
    for (int o = g63; o < 196608; o += GSZ63) {
      int mat = o / 98304; int r = o % 98304; int t = r / 49152; int rr = r % 49152;
      int k = rr / 384, j = rr % 384;
      const float* wih = p.Wih + (size_t)(t * 384 + j) * 128;
      const float* mw  = p.msg_W + (size_t)t * 128 * 272 + (mat * 128 + k);
      float acc = 0.f;
      for (int m = 0; m < 128; ++m) acc += wih[m] * mw[(size_t)m * 272];
      int mt = mat * 2 + t;
      p.Wp[(size_t)((mt * 16 + (k >> 3)) * 384 + j) * 8 + (k & 7)] = f2bf(acc);
    }
    // Whh -> bf16 packed (mt = 4+t)
    for (int o = g63; o < 98304; o += GSZ63) {
      int t = o / 49152; int rr = o % 49152; int k = rr / 384, j = rr % 384;
      float acc = p.Whh[(size_t)(t * 384 + j) * 128 + k];
      int mt = 4 + t;
      p.Wp[(size_t)((mt * 16 + (k >> 3)) * 384 + j) * 8 + (k & 7)] = f2bf(acc);
    }
    // W2T = (Wih@We)^T f32 [t][16][384]
    for (int o = g63; o < 12288; o += GSZ63) {
      int t = o / 6144; int rr = o % 6144; int k = rr / 384, j = rr % 384;
      const float* wih = p.Wih + (size_t)(t * 384 + j) * 128;
      const float* mw  = p.msg_W + (size_t)t * 128 * 272 + (256 + k);
      float acc = 0.f;
      for (int m = 0; m < 128; ++m) acc += wih[m] * mw[(size_t)m * 272];
      p.W2T[(size_t)(t * 16 + k) * 384 + j] = acc;
    }
    // bm2 = Wih @ msg_b
    for (int o = g63; o < 768; o += GSZ63) {
      int t = o / 384, j = o % 384;
      const float* wih = p.Wih + (size_t)(t * 384 + j) * 128;
      const float* mb = p.msg_b + t * 128;
      float acc = 0.f;
      for (int m = 0; m < 128; ++m) acc += wih[m] * mb[m];
      p.bm2[o] = acc;
    }
  }
  gsync(p.bar, mygen);

  // ---------- Stage B: in-degree histogram ----------
  if (blockIdx.x != 0) {
    for (int e = (blockIdx.x - 1) * NTHR + tid; e < 2048; e += (NBLK - 1) * NTHR)
      atomicAdd(&p.in_count[p.edst[e]], 1);
  }
  gsync(p.bar, mygen);

  // ---------- Stage C: prefix sum (block 0) ----------
  if (blockIdx.x == 0) {
    if (tid < 128) pfs[tid] = p.in_count[tid];
    __syncthreads();
    for (int off = 1; off < 128; off <<= 1) {
      int add = 0;
      if (tid < 128 && tid >= off) add = pfs[tid - off];
      __syncthreads();
      if (tid < 128) pfs[tid] += add;
      __syncthreads();
    }
    if (tid == 0) p.row_ptr[0] = 0;
    if (tid < 128) p.row_ptr[tid + 1] = pfs[tid];
  }
  gsync(p.bar, mygen);

  // ---------- Stage D: CSR scatter ----------
  for (int e = gtid; e < 2048; e += GSZ) {
    int dd = p.edst[e];
    int pos = atomicAdd(&p.cursor[dd], 1);
    int q = p.row_ptr[dd] + pos;
    p.col_src[q] = p.esrc[e];
    p.col_eid[q] = e;
  }
  gsync(p.bar, mygen);

  // ---------- Stage E: per-step deg / HeSum ----------
  for (int i = gtid; i < 16256; i += GSZ) {
    int s = i >> 7, v = i & 127;
    int rp0 = p.row_ptr[v], rp1 = p.row_ptr[v + 1];
    const unsigned char* al = p.alive + s * 128;
    float deg = 0.f; float hacc[16];
    #pragma unroll
    for (int k = 0; k < 16; ++k) hacc[k] = 0.f;
    for (int q = rp0; q < rp1; ++q) {
      int u = p.col_src[q];
      if (al[u]) {
        deg += 1.f;
        const float* hr = p.he + (size_t)p.col_eid[q] * 16;
        #pragma unroll
        for (int k = 0; k < 16; ++k) hacc[k] += hr[k];
      }
    }
    p.degs[i] = deg;
    float* ho = p.HeSum + (size_t)i * 16;
    #pragma unroll
    for (int k = 0; k < 16; ++k) ho[k] = hacc[k];
  }
  gsync(p.bar, mygen);

  // ---------- Stage F: has_edges + per-block CSR preload ----------
  for (int s = gtid; s < STEPS; s += GSZ) {
    float acc = 0.f;
    for (int v = 0; v < 128; ++v)
      acc += p.alive[s * 128 + v] ? p.degs[s * 128 + v] : 0.f;
    p.hasE[s] = (acc > 0.f) ? 1 : 0;
  }
  for (int vv = 0; vv < 2; ++vv) {
    int v = blockIdx.x * 2 + vv;
    int rp0 = p.row_ptr[v], rp1 = p.row_ptr[v + 1];
    if (tid == 0) { cntL[vv] = rp1 - rp0; rpL[vv] = rp0; }
    int n = rp1 - rp0; if (n > CAP) n = CAP;
    for (int q = tid; q < n; q += NTHR) colL[vv][q] = p.col_src[rp0 + q];
  }
  gsync(p.bar, mygen);   // publishes all setup data

  // ---------- Main loop ----------
  const float* cur = p.buf0; float* nxt = p.buf1;
  const int wave = tid >> 6, lane6 = tid & 63;
  const int nn = tid >> 7;             // node index for waves 0-3 threads (tid<256)
  const int dd_ = tid & 127;
  const int myv2 = blockIdx.x * 2;
  const uint4* Wp4 = (const uint4*)p.Wp;   // (mt*16+kc)*384 + j  per uint4

  // init local hv mirrors
  if (tid < 256) {
    float h0 = p.buf0[(size_t)(myv2 + nn) * 128 + dd_];
    hv_f[nn][dd_] = h0;
    hv_bf[nn][dd_] = f2bf(h0);
  }

  unsigned r = 0;
  for (int s = 0; s < STEPS; ++s) {
    for (int t = 0; t < 2; ++t) {
      r++;
      bpost(p.slots, r);

      // ---- pre-wait window: block-local GEMVs on waves 4-7 ----
      if (wave >= 4) {
        const int m = 1 + ((wave - 4) >> 1);    // 1=Wr, 2=Whh
        const int H = wave & 1;
        const uint4* WM = Wp4 + (size_t)(m * 2 + t) * 6144;
        float acc[6][2] = {};
        #pragma unroll
        for (int kc = 0; kc < 8; ++kc) {
          int kcg = H * 8 + kc;
          uint4 a0 = ((const uint4*)&hv_bf[0][0])[kcg];
          uint4 a1 = ((const uint4*)&hv_bf[1][0])[kcg];
          #pragma unroll
          for (int jj = 0; jj < 6; ++jj) {
            uint4 wv = WM[(size_t)kcg * 384 + lane6 + 64 * jj];
            acc[jj][0] = dot2bf(a0.x, wv.x, acc[jj][0]);
            acc[jj][0] = dot2bf(a0.y, wv.y, acc[jj][0]);
            acc[jj][0] = dot2bf(a0.z, wv.z, acc[jj][0]);
            acc[jj][0] = dot2bf(a0.w, wv.w, acc[jj][0]);
            acc[jj][1] = dot2bf(a1.x, wv.x, acc[jj][1]);
            acc[jj][1] = dot2bf(a1.y, wv.y, acc[jj][1]);
            acc[jj][1] = dot2bf(a1.z, wv.z, acc[jj][1]);
            acc[jj][1] = dot2bf(a1.w, wv.w, acc[jj][1]);
          }
        }
        float (*dst)[2][384] = (m == 1) ? pgr : pgh;
        #pragma unroll
        for (int jj = 0; jj < 6; ++jj) {
          dst[H][0][lane6 + 64 * jj] = acc[jj][0];
          dst[H][1][lane6 + 64 * jj] = acc[jj][1];
        }
        // He + biases: 768 slots over these 256 threads
        int base = tid - 256;
        #pragma unroll
        for (int ii = 0; ii < 3; ++ii) {
          int idx = base + 256 * ii;
          int n2 = (idx >= 384) ? 1 : 0;
          int j = idx - n2 * 384;
          int v = myv2 + n2;
          float deg = p.degs[s * 128 + v];
          float a = p.bih[t * 384 + j] + deg * p.bm2[t * 384 + j];
          const float* hs = p.HeSum + ((size_t)s * 128 + v) * 16;
          #pragma unroll
          for (int k2 = 0; k2 < 16; ++k2)
            a += hs[k2] * p.W2T[(size_t)(t * 16 + k2) * 384 + j];
          pgHe[n2][j] = a;
        }
      }

      bwait(p.slots, r);

      // ---- phase G: gather S (remote hv) on waves 0-3 ----
      if (tid < 256) {
        if (tid == 0) { victimL = p.victims[s]; hasEL = p.hasE[s]; }
        if (dd_ == 0) {
          degL[nn] = p.degs[s * 128 + myv2 + nn];
          aliveL[nn] = p.alive[s * 128 + myv2 + nn];
        }
        float acc = 0.f;
        int cnt = cntL[nn];
        int cmin = cnt < CAP ? cnt : CAP;
        int q = 0;
        for (; q + 8 <= cmin; q += 8) {
          int u0 = colL[nn][q],   u1 = colL[nn][q+1], u2 = colL[nn][q+2], u3 = colL[nn][q+3];
          int u4 = colL[nn][q+4], u5 = colL[nn][q+5], u6 = colL[nn][q+6], u7 = colL[nn][q+7];
          float f0 = ld_dev(&cur[(size_t)u0*128 + dd_]);
          float f1 = ld_dev(&cur[(size_t)u1*128 + dd_]);
          float f2 = ld_dev(&cur[(size_t)u2*128 + dd_]);
          float f3 = ld_dev(&cur[(size_t)u3*128 + dd_]);
          float f4 = ld_dev(&cur[(size_t)u4*128 + dd_]);
          float f5 = ld_dev(&cur[(size_t)u5*128 + dd_]);
          float f6 = ld_dev(&cur[(size_t)u6*128 + dd_]);
          float f7 = ld_dev(&cur[(size_t)u7*128 + dd_]);
          acc += ((f0+f1)+(f2+f3)) + ((f4+f5)+(f6+f7));
        }
        for (; q < cnt; ++q) {
          int u = (q < CAP) ? colL[nn][q] : p.col_src[rpL[nn] + q];
          acc += ld_dev(&cur[(size_t)u*128 + dd_]);
        }
        S_bf[nn][dd_] = f2bf(acc);
      }
      __syncthreads();

      // ---- phase Q: Wq . S on waves 0-3 (quarter-K each) ----
      if (wave < 4) {
        const uint4* WQ = Wp4 + (size_t)(0 * 2 + t) * 6144;
        float acc[6][2] = {};
        #pragma unroll
        for (int kc = 0; kc < 4; ++kc) {
          int kcg = wave * 4 + kc;
          uint4 a0 = ((const uint4*)&S_bf[0][0])[kcg];
          uint4 a1 = ((const uint4*)&S_bf[1][0])[kcg];
          #pragma unroll
          for (int jj = 0; jj < 6; ++jj) {
            uint4 wv = WQ[(size_t)kcg * 384 + lane6 + 64 * jj];
            acc[jj][0] = dot2bf(a0.x, wv.x, acc[jj][0]);
            acc[jj][0] = dot2bf(a0.y, wv.y, acc[jj][0]);
            acc[jj][0] = dot2bf(a0.z, wv.z, acc[jj][0]);
            acc[jj][0] = dot2bf(a0.w, wv.w, acc[jj][0]);
            acc[jj][1] = dot2bf(a1.x, wv.x, acc[jj][1]);
            acc[jj][1] = dot2bf(a1.y, wv.y, acc[jj][1]);
            acc[jj][1] = dot2bf(a1.z, wv.z, acc[jj][1]);
            acc[jj][1] = dot2bf(a1.w, wv.w, acc[jj][1]);
          }
        }
        #pragma unroll
        for (int jj = 0; jj < 6; ++jj) {
          pgq[wave][0][lane6 + 64 * jj] = acc[jj][0];
          pgq[wave][1][lane6 + 64 * jj] = acc[jj][1];
        }
      }
      __syncthreads();

      // ---- gates + hv update (waves 0-3) ----
      if (tid < 256) {
        float deg = degL[nn];
        int j0 = dd_, j1 = 128 + dd_, j2 = 256 + dd_;
        float gir = pgq[0][nn][j0] + pgq[1][nn][j0] + pgq[2][nn][j0] + pgq[3][nn][j0]
                  + deg * (pgr[0][nn][j0] + pgr[1][nn][j0]) + pgHe[nn][j0];
        float giz = pgq[0][nn][j1] + pgq[1][nn][j1] + pgq[2][nn][j1] + pgq[3][nn][j1]
                  + deg * (pgr[0][nn][j1] + pgr[1][nn][j1]) + pgHe[nn][j1];
        float gin = pgq[0][nn][j2] + pgq[1][nn][j2] + pgq[2][nn][j2] + pgq[3][nn][j2]
                  + deg * (pgr[0][nn][j2] + pgr[1][nn][j2]) + pgHe[nn][j2];
        float ghr = pgh[0][nn][j0] + pgh[1][nn][j0] + p.bhh[t * 384 + j0];
        float ghz = pgh[0][nn][j1] + pgh[1][nn][j1] + p.bhh[t * 384 + j1];
        float ghn = pgh[0][nn][j2] + pgh[1][nn][j2] + p.bhh[t * 384 + j2];
        float rr_ = 1.f / (1.f + expf(-(gir + ghr)));
        float z = 1.f / (1.f + expf(-(giz + ghz)));
        float nc = tanhf(gin + rr_ * ghn);
        float old = hv_f[nn][dd_];
        bool upd = (hasEL != 0) && (aliveL[nn] != 0);
        float nv = upd ? (1.f - z) * nc + z * old : old;
        int myv = myv2 + nn;
        if (t == 1 && myv == victimL) nv = 0.f;
        st_dev(&nxt[(size_t)myv * 128 + dd_], nv);
        hv_f[nn][dd_] = nv;
        hv_bf[nn][dd_] = f2bf(nv);
      }
      const float* tmp = nxt; nxt = (float*)cur; cur = tmp;
    }
  }

  // final publish + epilogue
  r++;
  bpost(p.slots, r);
  bwait(p.slots, r);
  if (blockIdx.x == 0 && tid < 128) {
    int surv = p.misc[0];
    p.out[tid] = ld_dev(&cur[(size_t)surv * 128 + tid]);
  }
}

extern "C" void kernel_launch(void* const* d_in, const int* in_sizes, int n_in,
                              void* d_out, int out_size, void* d_ws, size_t ws_size,
                              hipStream_t stream) {
  (void)in_sizes; (void)n_in; (void)out_size; (void)ws_size;
  GDParams p;
  p.node_types = (const int*)d_in[0];
  p.esrc = (const int*)d_in[1];
  p.edst = (const int*)d_in[2];
  p.he   = (const float*)d_in[3];
  p.enc_W = (const float*)d_in[4];
  p.enc_b = (const float*)d_in[5];
  p.msg_W = (const float*)d_in[6];
  p.msg_b = (const float*)d_in[7];
  p.Wih = (const float*)d_in[8];
  p.Whh = (const float*)d_in[9];
  p.bih = (const float*)d_in[10];
  p.bhh = (const float*)d_in[11];

  char* w = (char*)d_ws;
  auto take = [&](size_t n) { char* r = w; w += (n + 255) & ~(size_t)255; return r; };
  p.bar   = (unsigned*)take(256);
  p.slots = (unsigned*)take(256);
  p.buf0  = (float*)take(16384 * 4);
  p.buf1  = (float*)take(16384 * 4);
  p.g     = (float*)take(16256 * 4);
  p.Wp    = (unsigned short*)take((size_t)294912 * 2);
  p.W2T   = (float*)take(12288 * 4);
  p.bm2   = (float*)take(768 * 4);
  p.HeSum = (float*)take((size_t)16256 * 16 * 4);
  p.degs  = (float*)take(16256 * 4);
  p.alive = (unsigned char*)take(16384);
  p.hasE  = (unsigned char*)take(256);
  p.victims  = (int*)take(STEPS * 4);
  p.row_ptr  = (int*)take(129 * 4);
  p.in_count = (int*)take(128 * 4);
  p.cursor   = (int*)take(128 * 4);
  p.col_src  = (int*)take(2048 * 4);
  p.col_eid  = (int*)take(2048 * 4);
  p.misc     = (int*)take(256);
  p.out = (float*)d_out;

  (void)hipMemsetAsync(p.bar, 0, 512, stream);   // bar + slots must start at 0
  void* args[] = { (void*)&p };
  hipError_t err = hipLaunchCooperativeKernel(reinterpret_cast<void*>(gd_main),
                                              dim3(NBLK), dim3(NTHR), args, 0, stream);
  if (err != hipSuccess) {
    hipLaunchKernelGGL(gd_main, dim3(NBLK), dim3(NTHR), 0, stream, p);
  }
}